// Round 2
// baseline (162.276 us; speedup 1.0000x reference)
//
#include <hip/hip_runtime.h>
#include <hip/hip_bf16.h>

typedef _Float16 f16;
typedef _Float16 f16x2 __attribute__((ext_vector_type(2)));
typedef _Float16 f16x4 __attribute__((ext_vector_type(4)));
typedef _Float16 f16x8 __attribute__((ext_vector_type(8)));
typedef float f32x4 __attribute__((ext_vector_type(4)));

// Problem constants
#define NHEADS 6
#define NTOK 256      // tokens per window
#define NWINS 256     // windows (b_)
#define DIM 192
#define HD 32
#define C3 576        // 3*DIM
#define SCALE 0.17677669529663687f  // 1/sqrt(32)

// ---------------------------------------------------------------------------
// Kernel 1: CB[mg][h][q][k] = rpb_table[rpi[q,k], h] + mask[mg][q][k]  (f16)
// ---------------------------------------------------------------------------
__global__ __launch_bounds__(256) void prep_cb_kernel(const int* __restrict__ rpi,
                                                      const float* __restrict__ mask,
                                                      const float* __restrict__ rpb,
                                                      f16* __restrict__ cb) {
  int idx = blockIdx.x * 256 + threadIdx.x;
  int k = idx & 255;
  int q = (idx >> 8) & 255;
  int t = idx >> 16;       // t = mg*6 + h
  int h = t % 6;
  int mg = t / 6;
  float v = rpb[rpi[(q << 8) | k] * 6 + h] + mask[(mg << 16) | (q << 8) | k];
  cb[idx] = (f16)v;
}

// ---------------------------------------------------------------------------
// Kernel 2: W (192x192) fp32 -> f16
// ---------------------------------------------------------------------------
__global__ __launch_bounds__(256) void prep_w_kernel(const float* __restrict__ w,
                                                     f16* __restrict__ w16) {
  int i = blockIdx.x * 256 + threadIdx.x;
  if (i < DIM * DIM) w16[i] = (f16)w[i];
}

// ---------------------------------------------------------------------------
// Kernel 3: fused window attention. Block = (b, h, q-half). 256 thr = 4 waves.
// Wave w handles q rows [qh*128 + w*32, +32) in 2 chunks of 16.
//
// S^T = K . Q^T via mfma_f32_16x16x32_f16  (M=key, N=q, K=d=32)
//   A-frag (K): lane l -> key = kt*16 + (l&15), d = 8*(l>>4)+e
//   B-frag (Q^T): lane l -> q-col = (l&15), d = 8*(l>>4)+e
//   C: q-col = (l&15), key = kt*16 + 4*(l>>4) + r
// softmax in-lane + shfl_xor(16), shfl_xor(32).
// X^T = V^T . P^T via mfma_f32_16x16x16f16: P^T C-layout == B-operand layout.
// ---------------------------------------------------------------------------
__global__ __launch_bounds__(256, 4) void attn_kernel(const float* __restrict__ qkv,
                                                      const f16* __restrict__ cb,
                                                      f16* __restrict__ x16) {
  const int idx = blockIdx.x;
  const int b = idx & 255;
  const int qh = (idx >> 8) & 1;
  const int h = idx >> 9;
  const int tid = threadIdx.x;
  const int lane = tid & 63;
  const int wave = tid >> 6;
  const int g = lane >> 4;
  const int r16 = lane & 15;

  __shared__ f16 Klin[16 * 64 * 8];   // frag-linear: [kt][lane][8 d], 16 KB
  __shared__ f16 VT[32][264];         // [d][key] padded

  // ---- prefetch Q for this wave's 2 chunks (issue before staging loads) ----
  const int qbase = qh * 128 + wave * 32;
  const float* qp0 = qkv + (size_t)(b * NTOK + qbase + r16) * C3 + h * HD + g * 8;
  float4 qa0 = ((const float4*)qp0)[0];
  float4 qa1 = ((const float4*)qp0)[1];
  const float* qp1 = qp0 + 16 * C3;
  float4 qb0 = ((const float4*)qp1)[0];
  float4 qb1 = ((const float4*)qp1)[1];

  // ---- stage K and V, coalesced: 8 lanes cover one 128B row-segment ----
  {
    const int srow = tid >> 3;   // 0..31
    const int part = tid & 7;    // which 16B of the 128B segment
#pragma unroll
    for (int rg = 0; rg < 8; ++rg) {
      const int row = rg * 32 + srow;
      const float* kp = qkv + (size_t)(b * NTOK + row) * C3 + DIM + h * HD + part * 4;
      float4 kv4 = *(const float4*)kp;
      float4 vv4 = *(const float4*)(kp + DIM);
      f16x4 kf;
      kf[0] = (f16)kv4.x; kf[1] = (f16)kv4.y; kf[2] = (f16)kv4.z; kf[3] = (f16)kv4.w;
      *((f16x4*)&Klin[(((row >> 4) * 64) + (part >> 1) * 16 + (row & 15)) * 8 + (part & 1) * 4]) = kf;
      VT[part * 4 + 0][row] = (f16)vv4.x;
      VT[part * 4 + 1][row] = (f16)vv4.y;
      VT[part * 4 + 2][row] = (f16)vv4.z;
      VT[part * 4 + 3][row] = (f16)vv4.w;
    }
  }

  // convert Q to f16 (scaled) while staging loads are in flight
  f16x8 qfA, qfB;
  qfA[0] = (f16)(qa0.x * SCALE); qfA[1] = (f16)(qa0.y * SCALE);
  qfA[2] = (f16)(qa0.z * SCALE); qfA[3] = (f16)(qa0.w * SCALE);
  qfA[4] = (f16)(qa1.x * SCALE); qfA[5] = (f16)(qa1.y * SCALE);
  qfA[6] = (f16)(qa1.z * SCALE); qfA[7] = (f16)(qa1.w * SCALE);
  qfB[0] = (f16)(qb0.x * SCALE); qfB[1] = (f16)(qb0.y * SCALE);
  qfB[2] = (f16)(qb0.z * SCALE); qfB[3] = (f16)(qb0.w * SCALE);
  qfB[4] = (f16)(qb1.x * SCALE); qfB[5] = (f16)(qb1.y * SCALE);
  qfB[6] = (f16)(qb1.z * SCALE); qfB[7] = (f16)(qb1.w * SCALE);

  __syncthreads();

  const size_t cb_base = ((size_t)((b & 15) * 6 + h)) << 16;

#pragma unroll
  for (int c = 0; c < 2; ++c) {
    const int qrow = qbase + c * 16 + r16;
    const f16x8 qf = (c == 0) ? qfA : qfB;
    const f16* cbp = cb + cb_base + ((size_t)qrow << 8) + g * 4;

    f32x4 acc[16];
#pragma unroll
    for (int kt = 0; kt < 16; ++kt) {
      acc[kt][0] = 0.f; acc[kt][1] = 0.f; acc[kt][2] = 0.f; acc[kt][3] = 0.f;
    }

    // pipelined: cv half0 loads -> mfma 0..7 -> cv half1 loads -> bias0 -> mfma 8..15 -> bias1
    f16x4 cv0[8], cv1[8];
#pragma unroll
    for (int kt = 0; kt < 8; ++kt) cv0[kt] = *((const f16x4*)(cbp + kt * 16));
#pragma unroll
    for (int kt = 0; kt < 8; ++kt) {
      f16x8 af = *((const f16x8*)&Klin[(kt * 64 + lane) * 8]);
      acc[kt] = __builtin_amdgcn_mfma_f32_16x16x32_f16(af, qf, acc[kt], 0, 0, 0);
    }
#pragma unroll
    for (int kt = 0; kt < 8; ++kt) cv1[kt] = *((const f16x4*)(cbp + (8 + kt) * 16));
    float m = -1e30f;
#pragma unroll
    for (int kt = 0; kt < 8; ++kt) {
#pragma unroll
      for (int r = 0; r < 4; ++r) {
        acc[kt][r] += (float)cv0[kt][r];
        m = fmaxf(m, acc[kt][r]);
      }
    }
#pragma unroll
    for (int kt = 8; kt < 16; ++kt) {
      f16x8 af = *((const f16x8*)&Klin[(kt * 64 + lane) * 8]);
      acc[kt] = __builtin_amdgcn_mfma_f32_16x16x32_f16(af, qf, acc[kt], 0, 0, 0);
    }
#pragma unroll
    for (int kt = 8; kt < 16; ++kt) {
#pragma unroll
      for (int r = 0; r < 4; ++r) {
        acc[kt][r] += (float)cv1[kt - 8][r];
        m = fmaxf(m, acc[kt][r]);
      }
    }
    m = fmaxf(m, __shfl_xor(m, 16));
    m = fmaxf(m, __shfl_xor(m, 32));

    float s = 0.f;
#pragma unroll
    for (int kt = 0; kt < 16; ++kt) {
#pragma unroll
      for (int r = 0; r < 4; ++r) {
        float p = __expf(acc[kt][r] - m);
        acc[kt][r] = p;
        s += p;
      }
    }
    s += __shfl_xor(s, 16);
    s += __shfl_xor(s, 32);
    const float rinv = 1.0f / s;

    // PV: X^T[d][q] = sum_k V^T[d][k] * P^T[k][q]
    f32x4 xacc[2];
#pragma unroll
    for (int dt = 0; dt < 2; ++dt) {
      xacc[dt][0] = 0.f; xacc[dt][1] = 0.f; xacc[dt][2] = 0.f; xacc[dt][3] = 0.f;
    }
#pragma unroll
    for (int kt = 0; kt < 16; ++kt) {
      f16x4 pf;
      pf[0] = (f16)acc[kt][0]; pf[1] = (f16)acc[kt][1];
      pf[2] = (f16)acc[kt][2]; pf[3] = (f16)acc[kt][3];
#pragma unroll
      for (int dt = 0; dt < 2; ++dt) {
        f16x4 vf = *((const f16x4*)&VT[dt * 16 + r16][kt * 16 + g * 4]);
        xacc[dt] = __builtin_amdgcn_mfma_f32_16x16x16f16(vf, pf, xacc[dt], 0, 0, 0);
      }
    }

    // write x (f16) [b][token][192], normalized
    f16* xp = x16 + (size_t)(b * NTOK + qrow) * DIM + h * HD;
#pragma unroll
    for (int dt = 0; dt < 2; ++dt) {
      f16x4 xo;
      xo[0] = (f16)(xacc[dt][0] * rinv); xo[1] = (f16)(xacc[dt][1] * rinv);
      xo[2] = (f16)(xacc[dt][2] * rinv); xo[3] = (f16)(xacc[dt][3] * rinv);
      *((f16x4*)(xp + dt * 16 + g * 4)) = xo;
    }
  }
}

// ---------------------------------------------------------------------------
// Kernel 4: out[m][j] = sum_c X16[m][c] * W16[j][c] + pb[j]
// ---------------------------------------------------------------------------
__global__ __launch_bounds__(256) void proj_kernel(const f16* __restrict__ x16,
                                                   const f16* __restrict__ w16,
                                                   const float* __restrict__ pb,
                                                   float* __restrict__ out) {
  const int lane = threadIdx.x & 63;
  const int wave = threadIdx.x >> 6;
  const int g = lane >> 4;
  const int r16 = lane & 15;
  const int m0 = blockIdx.x * 64 + wave * 16;

  f32x4 acc[12];
#pragma unroll
  for (int jt = 0; jt < 12; ++jt) {
    acc[jt][0] = 0.f; acc[jt][1] = 0.f; acc[jt][2] = 0.f; acc[jt][3] = 0.f;
  }
#pragma unroll
  for (int cc = 0; cc < 6; ++cc) {
    f16x8 af = *((const f16x8*)(x16 + (size_t)(m0 + r16) * DIM + cc * 32 + g * 8));
#pragma unroll
    for (int jt = 0; jt < 12; ++jt) {
      f16x8 bf = *((const f16x8*)(w16 + (size_t)(jt * 16 + r16) * DIM + cc * 32 + g * 8));
      acc[jt] = __builtin_amdgcn_mfma_f32_16x16x32_f16(af, bf, acc[jt], 0, 0, 0);
    }
  }
#pragma unroll
  for (int jt = 0; jt < 12; ++jt) {
    int j = jt * 16 + r16;
    float bias = pb[j];
#pragma unroll
    for (int r = 0; r < 4; ++r) {
      out[(size_t)(m0 + g * 4 + r) * DIM + j] = acc[jt][r] + bias;
    }
  }
}

// ---------------------------------------------------------------------------
extern "C" void kernel_launch(void* const* d_in, const int* in_sizes, int n_in,
                              void* d_out, int out_size, void* d_ws, size_t ws_size,
                              hipStream_t stream) {
  const float* qkv  = (const float*)d_in[0];
  const int*   rpi  = (const int*)d_in[1];
  const float* mask = (const float*)d_in[2];
  const float* rpb  = (const float*)d_in[3];
  const float* pw   = (const float*)d_in[4];
  const float* pbv  = (const float*)d_in[5];
  float* out = (float*)d_out;

  char* ws = (char*)d_ws;
  f16* cb  = (f16*)ws;                               // 12,582,912 B
  f16* x16 = (f16*)(ws + 12582912);                  // 25,165,824 B
  f16* w16 = (f16*)(ws + 12582912 + 25165824);       // 73,728 B

  prep_cb_kernel<<<24576, 256, 0, stream>>>(rpi, mask, rpb, cb);
  prep_w_kernel<<<144, 256, 0, stream>>>(pw, w16);
  attn_kernel<<<3072, 256, 0, stream>>>(qkv, cb, x16);
  proj_kernel<<<1024, 256, 0, stream>>>(x16, w16, pbv, out);
}

// Round 3
// 139.069 us; speedup vs baseline: 1.1669x; 1.1669x over previous
//
#include <hip/hip_runtime.h>
#include <hip/hip_bf16.h>

typedef _Float16 f16;
typedef _Float16 f16x2 __attribute__((ext_vector_type(2)));
typedef _Float16 f16x4 __attribute__((ext_vector_type(4)));
typedef _Float16 f16x8 __attribute__((ext_vector_type(8)));
typedef float f32x4 __attribute__((ext_vector_type(4)));

// Problem constants
#define NHEADS 6
#define NTOK 256      // tokens per window
#define NWINS 256     // windows (b_)
#define DIM 192
#define HD 32
#define C3 576        // 3*DIM
#define SCALE 0.17677669529663687f  // 1/sqrt(32)

// ---------------------------------------------------------------------------
// Kernel 1: CB[mg][h][q][k] = rpb_table[rpi[q,k], h] + mask[mg][q][k]  (f16)
// ---------------------------------------------------------------------------
__global__ __launch_bounds__(256) void prep_cb_kernel(const int* __restrict__ rpi,
                                                      const float* __restrict__ mask,
                                                      const float* __restrict__ rpb,
                                                      f16* __restrict__ cb) {
  int idx = blockIdx.x * 256 + threadIdx.x;
  int k = idx & 255;
  int q = (idx >> 8) & 255;
  int t = idx >> 16;       // t = mg*6 + h
  int h = t % 6;
  int mg = t / 6;
  float v = rpb[rpi[(q << 8) | k] * 6 + h] + mask[(mg << 16) | (q << 8) | k];
  cb[idx] = (f16)v;
}

// ---------------------------------------------------------------------------
// Kernel 2: W (192x192) fp32 -> f16
// ---------------------------------------------------------------------------
__global__ __launch_bounds__(256) void prep_w_kernel(const float* __restrict__ w,
                                                     f16* __restrict__ w16) {
  int i = blockIdx.x * 256 + threadIdx.x;
  if (i < DIM * DIM) w16[i] = (f16)w[i];
}

// ---------------------------------------------------------------------------
// Kernel 3: fused window attention. Block = (b, h, q-half). 256 thr = 4 waves.
// Wave w handles q rows [qh*128 + w*32, +32) in 2 chunks of 16.
// __launch_bounds__(256,3): VGPR cap ~170 -> NO SPILLS (r2 lesson: (256,4)
// forced VGPR=64 and spilled ~130 MB of scratch traffic).
//
// S^T = K . Q^T via mfma_f32_16x16x32_f16  (M=key, N=q, K=d=32)
//   C: q-col = (l&15), key = kt*16 + 4*(l>>4) + r
// softmax in-lane + shfl_xor(16), shfl_xor(32).
// X^T = V^T . P^T via mfma_f32_16x16x16f16: P^T C-layout == B-operand layout.
// ---------------------------------------------------------------------------
__global__ __launch_bounds__(256, 3) void attn_kernel(const float* __restrict__ qkv,
                                                      const f16* __restrict__ cb,
                                                      f16* __restrict__ x16) {
  const int idx = blockIdx.x;
  const int b = idx & 255;
  const int qh = (idx >> 8) & 1;
  const int h = idx >> 9;
  const int tid = threadIdx.x;
  const int lane = tid & 63;
  const int wave = tid >> 6;
  const int g = lane >> 4;
  const int r16 = lane & 15;

  __shared__ f16 Klin[16 * 64 * 8];   // frag-linear: [kt][lane][8 d], 16 KB
  __shared__ f16 VT[32][264];         // [d][key] padded

  // ---- prefetch Q for this wave's 2 chunks (issue before staging loads) ----
  const int qbase = qh * 128 + wave * 32;
  const float* qp0 = qkv + (size_t)(b * NTOK + qbase + r16) * C3 + h * HD + g * 8;
  float4 qa0 = ((const float4*)qp0)[0];
  float4 qa1 = ((const float4*)qp0)[1];
  const float* qp1 = qp0 + 16 * C3;
  float4 qb0 = ((const float4*)qp1)[0];
  float4 qb1 = ((const float4*)qp1)[1];

  // ---- stage K and V, coalesced: 8 lanes cover one 128B row-segment ----
  {
    const int srow = tid >> 3;   // 0..31
    const int part = tid & 7;    // which 16B of the 128B segment
#pragma unroll
    for (int rg = 0; rg < 8; ++rg) {
      const int row = rg * 32 + srow;
      const float* kp = qkv + (size_t)(b * NTOK + row) * C3 + DIM + h * HD + part * 4;
      float4 kv4 = *(const float4*)kp;
      float4 vv4 = *(const float4*)(kp + DIM);
      f16x4 kf;
      kf[0] = (f16)kv4.x; kf[1] = (f16)kv4.y; kf[2] = (f16)kv4.z; kf[3] = (f16)kv4.w;
      *((f16x4*)&Klin[(((row >> 4) * 64) + (part >> 1) * 16 + (row & 15)) * 8 + (part & 1) * 4]) = kf;
      VT[part * 4 + 0][row] = (f16)vv4.x;
      VT[part * 4 + 1][row] = (f16)vv4.y;
      VT[part * 4 + 2][row] = (f16)vv4.z;
      VT[part * 4 + 3][row] = (f16)vv4.w;
    }
  }

  // convert Q to f16 (scaled) while staging loads are in flight
  f16x8 qfA, qfB;
  qfA[0] = (f16)(qa0.x * SCALE); qfA[1] = (f16)(qa0.y * SCALE);
  qfA[2] = (f16)(qa0.z * SCALE); qfA[3] = (f16)(qa0.w * SCALE);
  qfA[4] = (f16)(qa1.x * SCALE); qfA[5] = (f16)(qa1.y * SCALE);
  qfA[6] = (f16)(qa1.z * SCALE); qfA[7] = (f16)(qa1.w * SCALE);
  qfB[0] = (f16)(qb0.x * SCALE); qfB[1] = (f16)(qb0.y * SCALE);
  qfB[2] = (f16)(qb0.z * SCALE); qfB[3] = (f16)(qb0.w * SCALE);
  qfB[4] = (f16)(qb1.x * SCALE); qfB[5] = (f16)(qb1.y * SCALE);
  qfB[6] = (f16)(qb1.z * SCALE); qfB[7] = (f16)(qb1.w * SCALE);

  __syncthreads();

  const size_t cb_base = ((size_t)((b & 15) * 6 + h)) << 16;

#pragma unroll
  for (int c = 0; c < 2; ++c) {
    const int qrow = qbase + c * 16 + r16;
    const f16x8 qf = (c == 0) ? qfA : qfB;
    const f16* cbp = cb + cb_base + ((size_t)qrow << 8) + g * 4;

    f32x4 acc[16];
#pragma unroll
    for (int kt = 0; kt < 16; ++kt) {
      acc[kt][0] = 0.f; acc[kt][1] = 0.f; acc[kt][2] = 0.f; acc[kt][3] = 0.f;
    }

    // 4-group pipeline: issue 4 bias loads -> 4 MFMAs -> 4 bias-adds + max
    // (keeps only 8 cv VGPRs live vs 32 for full prefetch)
    float m = -1e30f;
#pragma unroll
    for (int kh = 0; kh < 4; ++kh) {
      f16x4 cv[4];
#pragma unroll
      for (int i = 0; i < 4; ++i) cv[i] = *((const f16x4*)(cbp + (kh * 4 + i) * 16));
#pragma unroll
      for (int i = 0; i < 4; ++i) {
        const int kt = kh * 4 + i;
        f16x8 af = *((const f16x8*)&Klin[(kt * 64 + lane) * 8]);
        acc[kt] = __builtin_amdgcn_mfma_f32_16x16x32_f16(af, qf, acc[kt], 0, 0, 0);
      }
#pragma unroll
      for (int i = 0; i < 4; ++i) {
        const int kt = kh * 4 + i;
#pragma unroll
        for (int r = 0; r < 4; ++r) {
          acc[kt][r] += (float)cv[i][r];
          m = fmaxf(m, acc[kt][r]);
        }
      }
    }
    m = fmaxf(m, __shfl_xor(m, 16));
    m = fmaxf(m, __shfl_xor(m, 32));

    float s = 0.f;
#pragma unroll
    for (int kt = 0; kt < 16; ++kt) {
#pragma unroll
      for (int r = 0; r < 4; ++r) {
        float p = __expf(acc[kt][r] - m);
        acc[kt][r] = p;
        s += p;
      }
    }
    s += __shfl_xor(s, 16);
    s += __shfl_xor(s, 32);
    const float rinv = 1.0f / s;

    // PV: X^T[d][q] = sum_k V^T[d][k] * P^T[k][q]
    f32x4 xacc[2];
#pragma unroll
    for (int dt = 0; dt < 2; ++dt) {
      xacc[dt][0] = 0.f; xacc[dt][1] = 0.f; xacc[dt][2] = 0.f; xacc[dt][3] = 0.f;
    }
#pragma unroll
    for (int kt = 0; kt < 16; ++kt) {
      f16x4 pf;
      pf[0] = (f16)acc[kt][0]; pf[1] = (f16)acc[kt][1];
      pf[2] = (f16)acc[kt][2]; pf[3] = (f16)acc[kt][3];
#pragma unroll
      for (int dt = 0; dt < 2; ++dt) {
        f16x4 vf = *((const f16x4*)&VT[dt * 16 + r16][kt * 16 + g * 4]);
        xacc[dt] = __builtin_amdgcn_mfma_f32_16x16x16f16(vf, pf, xacc[dt], 0, 0, 0);
      }
    }

    // write x (f16) [b][token][192], normalized
    f16* xp = x16 + (size_t)(b * NTOK + qrow) * DIM + h * HD;
#pragma unroll
    for (int dt = 0; dt < 2; ++dt) {
      f16x4 xo;
      xo[0] = (f16)(xacc[dt][0] * rinv); xo[1] = (f16)(xacc[dt][1] * rinv);
      xo[2] = (f16)(xacc[dt][2] * rinv); xo[3] = (f16)(xacc[dt][3] * rinv);
      *((f16x4*)(xp + dt * 16 + g * 4)) = xo;
    }
  }
}

// ---------------------------------------------------------------------------
// Kernel 4: out[m][j] = sum_c X16[m][c] * W16[j][c] + pb[j]
// ---------------------------------------------------------------------------
__global__ __launch_bounds__(256) void proj_kernel(const f16* __restrict__ x16,
                                                   const f16* __restrict__ w16,
                                                   const float* __restrict__ pb,
                                                   float* __restrict__ out) {
  const int lane = threadIdx.x & 63;
  const int wave = threadIdx.x >> 6;
  const int g = lane >> 4;
  const int r16 = lane & 15;
  const int m0 = blockIdx.x * 64 + wave * 16;

  f32x4 acc[12];
#pragma unroll
  for (int jt = 0; jt < 12; ++jt) {
    acc[jt][0] = 0.f; acc[jt][1] = 0.f; acc[jt][2] = 0.f; acc[jt][3] = 0.f;
  }
#pragma unroll
  for (int cc = 0; cc < 6; ++cc) {
    f16x8 af = *((const f16x8*)(x16 + (size_t)(m0 + r16) * DIM + cc * 32 + g * 8));
#pragma unroll
    for (int jt = 0; jt < 12; ++jt) {
      f16x8 bf = *((const f16x8*)(w16 + (size_t)(jt * 16 + r16) * DIM + cc * 32 + g * 8));
      acc[jt] = __builtin_amdgcn_mfma_f32_16x16x32_f16(af, bf, acc[jt], 0, 0, 0);
    }
  }
#pragma unroll
  for (int jt = 0; jt < 12; ++jt) {
    int j = jt * 16 + r16;
    float bias = pb[j];
#pragma unroll
    for (int r = 0; r < 4; ++r) {
      out[(size_t)(m0 + g * 4 + r) * DIM + j] = acc[jt][r] + bias;
    }
  }
}

// ---------------------------------------------------------------------------
extern "C" void kernel_launch(void* const* d_in, const int* in_sizes, int n_in,
                              void* d_out, int out_size, void* d_ws, size_t ws_size,
                              hipStream_t stream) {
  const float* qkv  = (const float*)d_in[0];
  const int*   rpi  = (const int*)d_in[1];
  const float* mask = (const float*)d_in[2];
  const float* rpb  = (const float*)d_in[3];
  const float* pw   = (const float*)d_in[4];
  const float* pbv  = (const float*)d_in[5];
  float* out = (float*)d_out;

  char* ws = (char*)d_ws;
  f16* cb  = (f16*)ws;                               // 12,582,912 B
  f16* x16 = (f16*)(ws + 12582912);                  // 25,165,824 B
  f16* w16 = (f16*)(ws + 12582912 + 25165824);       // 73,728 B

  prep_cb_kernel<<<24576, 256, 0, stream>>>(rpi, mask, rpb, cb);
  prep_w_kernel<<<144, 256, 0, stream>>>(pw, w16);
  attn_kernel<<<3072, 256, 0, stream>>>(qkv, cb, x16);
  proj_kernel<<<1024, 256, 0, stream>>>(x16, w16, pbv, out);
}

// Round 4
// 126.592 us; speedup vs baseline: 1.2819x; 1.0986x over previous
//
#include <hip/hip_runtime.h>
#include <hip/hip_bf16.h>

typedef _Float16 f16;
typedef _Float16 f16x2 __attribute__((ext_vector_type(2)));
typedef _Float16 f16x4 __attribute__((ext_vector_type(4)));
typedef _Float16 f16x8 __attribute__((ext_vector_type(8)));
typedef float f32x4 __attribute__((ext_vector_type(4)));

// Problem constants
#define NHEADS 6
#define NTOK 256      // tokens per window
#define NWINS 256     // windows (b_)
#define DIM 192
#define HD 32
#define C3 576        // 3*DIM
#define SCALE 0.17677669529663687f  // 1/sqrt(32)

// ---------------------------------------------------------------------------
// Kernel 1: CB[mg][h][q][k] = rpb_table[rpi[q,k], h] + mask[mg][q][k]  (f16)
// ---------------------------------------------------------------------------
__global__ __launch_bounds__(256) void prep_cb_kernel(const int* __restrict__ rpi,
                                                      const float* __restrict__ mask,
                                                      const float* __restrict__ rpb,
                                                      f16* __restrict__ cb) {
  int idx = blockIdx.x * 256 + threadIdx.x;
  int k = idx & 255;
  int q = (idx >> 8) & 255;
  int t = idx >> 16;       // t = mg*6 + h
  int h = t % 6;
  int mg = t / 6;
  float v = rpb[rpi[(q << 8) | k] * 6 + h] + mask[(mg << 16) | (q << 8) | k];
  cb[idx] = (f16)v;
}

// ---------------------------------------------------------------------------
// Kernel 2: W (192x192) fp32 -> f16
// ---------------------------------------------------------------------------
__global__ __launch_bounds__(256) void prep_w_kernel(const float* __restrict__ w,
                                                     f16* __restrict__ w16) {
  int i = blockIdx.x * 256 + threadIdx.x;
  if (i < DIM * DIM) w16[i] = (f16)w[i];
}

// ---------------------------------------------------------------------------
// Kernel 3: fused window attention. Block = (b, h, q-half). 256 thr = 4 waves.
// Wave w handles q rows [qh*128 + w*32, +32) in 2 chunks of 16.
//
// r4 changes (kill per-wave serial latency):
//  - staging loads batch-issued (2 groups of 8 float4-pairs) -> ~2 serial
//    HBM waits instead of 8 dependent load->convert->write iterations
//  - all 16 cb bias loads for chunk0 prefetched to regs BEFORE the barrier;
//    chunk1's issued during chunk0 compute -> L3 latency hidden
//  - Klin staging writes XOR-swizzled (r ^ (gg<<2)): 4-way -> 2-way (free)
//  - VT column swizzle (col ^ ((d&7)<<2)): 8-way -> ~4-way write conflicts
//
// S^T = K . Q^T via mfma_f32_16x16x32_f16; C: q-col=(l&15), key=kt*16+4*(l>>4)+r
// X^T = V^T . P^T via mfma_f32_16x16x16f16: P^T C-layout == B-operand layout.
// ---------------------------------------------------------------------------
__global__ __launch_bounds__(256, 3) void attn_kernel(const float* __restrict__ qkv,
                                                      const f16* __restrict__ cb,
                                                      f16* __restrict__ x16) {
  const int idx = blockIdx.x;
  const int b = idx & 255;
  const int qh = (idx >> 8) & 1;
  const int h = idx >> 9;
  const int tid = threadIdx.x;
  const int lane = tid & 63;
  const int wave = tid >> 6;
  const int g = lane >> 4;
  const int r16 = lane & 15;

  __shared__ f16 Klin[16 * 64 * 8];   // frag-linear (XOR-swizzled), 16 KB
  __shared__ f16 VT[32][264];         // [d][key^((d&7)<<2)] padded

  const int qbase = qh * 128 + wave * 32;
  const size_t cb_base = ((size_t)((b & 15) * 6 + h)) << 16;
  const f16* cbp0 = cb + cb_base + ((size_t)(qbase + r16) << 8) + g * 4;

  // ---- batch-issue staging loads: group A (rows 0..127), group B (128..255)
  const int srow = tid >> 3;   // 0..31
  const int part = tid & 7;    // which 16B of the 128B row segment
  const float* kbase = qkv + (size_t)(b * NTOK + srow) * C3 + DIM + h * HD + part * 4;
  float4 ka[4], va[4], kb[4], vb[4];
#pragma unroll
  for (int rg = 0; rg < 4; ++rg) {
    const float* kp = kbase + (size_t)(rg * 32) * C3;
    ka[rg] = *(const float4*)kp;
    va[rg] = *(const float4*)(kp + DIM);
  }
#pragma unroll
  for (int rg = 0; rg < 4; ++rg) {
    const float* kp = kbase + (size_t)(rg * 32 + 128) * C3;
    kb[rg] = *(const float4*)kp;
    vb[rg] = *(const float4*)(kp + DIM);
  }

  // ---- prefetch chunk0 bias (16 x 8B, L2/L3) while staging loads fly ----
  f16x4 cv0[16];
#pragma unroll
  for (int i = 0; i < 16; ++i) cv0[i] = *((const f16x4*)(cbp0 + i * 16));

  // ---- Q loads for both chunks ----
  const float* qp0 = qkv + (size_t)(b * NTOK + qbase + r16) * C3 + h * HD + g * 8;
  float4 qa0 = ((const float4*)qp0)[0];
  float4 qa1 = ((const float4*)qp0)[1];
  const float* qp1 = qp0 + 16 * C3;
  float4 qb0 = ((const float4*)qp1)[0];
  float4 qb1 = ((const float4*)qp1)[1];

  // ---- convert + LDS-write staging groups (in load order) ----
  const int gg = part >> 1;
  const int half = part & 1;
#pragma unroll
  for (int rg = 0; rg < 4; ++rg) {
    const int row = rg * 32 + srow;
    const int slot = ((row >> 4) * 64) + gg * 16 + ((row & 15) ^ (gg << 2));
    f16x4 kf;
    kf[0] = (f16)ka[rg].x; kf[1] = (f16)ka[rg].y; kf[2] = (f16)ka[rg].z; kf[3] = (f16)ka[rg].w;
    *((f16x4*)&Klin[slot * 8 + half * 4]) = kf;
    const int d0 = part * 4;
    VT[d0 + 0][row ^ (((d0 + 0) & 7) << 2)] = (f16)va[rg].x;
    VT[d0 + 1][row ^ (((d0 + 1) & 7) << 2)] = (f16)va[rg].y;
    VT[d0 + 2][row ^ (((d0 + 2) & 7) << 2)] = (f16)va[rg].z;
    VT[d0 + 3][row ^ (((d0 + 3) & 7) << 2)] = (f16)va[rg].w;
  }
#pragma unroll
  for (int rg = 0; rg < 4; ++rg) {
    const int row = rg * 32 + srow + 128;
    const int slot = ((row >> 4) * 64) + gg * 16 + ((row & 15) ^ (gg << 2));
    f16x4 kf;
    kf[0] = (f16)kb[rg].x; kf[1] = (f16)kb[rg].y; kf[2] = (f16)kb[rg].z; kf[3] = (f16)kb[rg].w;
    *((f16x4*)&Klin[slot * 8 + half * 4]) = kf;
    const int d0 = part * 4;
    VT[d0 + 0][row ^ (((d0 + 0) & 7) << 2)] = (f16)vb[rg].x;
    VT[d0 + 1][row ^ (((d0 + 1) & 7) << 2)] = (f16)vb[rg].y;
    VT[d0 + 2][row ^ (((d0 + 2) & 7) << 2)] = (f16)vb[rg].z;
    VT[d0 + 3][row ^ (((d0 + 3) & 7) << 2)] = (f16)vb[rg].w;
  }

  // convert Q to f16 (scaled)
  f16x8 qfA, qfB;
  qfA[0] = (f16)(qa0.x * SCALE); qfA[1] = (f16)(qa0.y * SCALE);
  qfA[2] = (f16)(qa0.z * SCALE); qfA[3] = (f16)(qa0.w * SCALE);
  qfA[4] = (f16)(qa1.x * SCALE); qfA[5] = (f16)(qa1.y * SCALE);
  qfA[6] = (f16)(qa1.z * SCALE); qfA[7] = (f16)(qa1.w * SCALE);
  qfB[0] = (f16)(qb0.x * SCALE); qfB[1] = (f16)(qb0.y * SCALE);
  qfB[2] = (f16)(qb0.z * SCALE); qfB[3] = (f16)(qb0.w * SCALE);
  qfB[4] = (f16)(qb1.x * SCALE); qfB[5] = (f16)(qb1.y * SCALE);
  qfB[6] = (f16)(qb1.z * SCALE); qfB[7] = (f16)(qb1.w * SCALE);

  __syncthreads();

  // swizzled Klin read offset for this lane: kt*64 + (lane&48) + (r ^ (gg<<2))
  const int krd = (lane & 48) + ((lane & 15) ^ ((lane >> 2) & 12));

  f16x4 cv1[16];

#pragma unroll
  for (int c = 0; c < 2; ++c) {
    const int qrow = qbase + c * 16 + r16;
    const f16x8 qf = (c == 0) ? qfA : qfB;

    f32x4 acc[16];
#pragma unroll
    for (int kt = 0; kt < 16; ++kt) {
      acc[kt][0] = 0.f; acc[kt][1] = 0.f; acc[kt][2] = 0.f; acc[kt][3] = 0.f;
    }
#pragma unroll
    for (int kt = 0; kt < 16; ++kt) {
      f16x8 af = *((const f16x8*)&Klin[(kt * 64 + krd) * 8]);
      acc[kt] = __builtin_amdgcn_mfma_f32_16x16x32_f16(af, qf, acc[kt], 0, 0, 0);
    }

    // bias + max (cv for this chunk already in regs)
    float m = -1e30f;
#pragma unroll
    for (int kt = 0; kt < 16; ++kt) {
      f16x4 cv = (c == 0) ? cv0[kt] : cv1[kt];
#pragma unroll
      for (int r = 0; r < 4; ++r) {
        acc[kt][r] += (float)cv[r];
        m = fmaxf(m, acc[kt][r]);
      }
    }

    // issue next chunk's bias loads now (hide L3 latency under softmax+PV)
    if (c == 0) {
      const f16* cbp1 = cbp0 + 16 * 256;
#pragma unroll
      for (int i = 0; i < 16; ++i) cv1[i] = *((const f16x4*)(cbp1 + i * 16));
    }

    m = fmaxf(m, __shfl_xor(m, 16));
    m = fmaxf(m, __shfl_xor(m, 32));

    float s = 0.f;
#pragma unroll
    for (int kt = 0; kt < 16; ++kt) {
#pragma unroll
      for (int r = 0; r < 4; ++r) {
        float p = __expf(acc[kt][r] - m);
        acc[kt][r] = p;
        s += p;
      }
    }
    s += __shfl_xor(s, 16);
    s += __shfl_xor(s, 32);
    const float rinv = 1.0f / s;

    // PV: X^T[d][q] = sum_k V^T[d][k] * P^T[k][q]
    f32x4 xacc[2];
#pragma unroll
    for (int dt = 0; dt < 2; ++dt) {
      xacc[dt][0] = 0.f; xacc[dt][1] = 0.f; xacc[dt][2] = 0.f; xacc[dt][3] = 0.f;
    }
#pragma unroll
    for (int kt = 0; kt < 16; ++kt) {
      f16x4 pf;
      pf[0] = (f16)acc[kt][0]; pf[1] = (f16)acc[kt][1];
      pf[2] = (f16)acc[kt][2]; pf[3] = (f16)acc[kt][3];
#pragma unroll
      for (int dt = 0; dt < 2; ++dt) {
        const int vrow = dt * 16 + r16;
        const int col = (kt * 16 + g * 4) ^ ((r16 & 7) << 2);
        f16x4 vf = *((const f16x4*)&VT[vrow][col]);
        xacc[dt] = __builtin_amdgcn_mfma_f32_16x16x16f16(vf, pf, xacc[dt], 0, 0, 0);
      }
    }

    // write x (f16) [b][token][192], normalized
    f16* xp = x16 + (size_t)(b * NTOK + qrow) * DIM + h * HD;
#pragma unroll
    for (int dt = 0; dt < 2; ++dt) {
      f16x4 xo;
      xo[0] = (f16)(xacc[dt][0] * rinv); xo[1] = (f16)(xacc[dt][1] * rinv);
      xo[2] = (f16)(xacc[dt][2] * rinv); xo[3] = (f16)(xacc[dt][3] * rinv);
      *((f16x4*)(xp + dt * 16 + g * 4)) = xo;
    }
  }
}

// ---------------------------------------------------------------------------
// Kernel 4: out[m][j] = sum_c X16[m][c] * W16[j][c] + pb[j]
// ---------------------------------------------------------------------------
__global__ __launch_bounds__(256) void proj_kernel(const f16* __restrict__ x16,
                                                   const f16* __restrict__ w16,
                                                   const float* __restrict__ pb,
                                                   float* __restrict__ out) {
  const int lane = threadIdx.x & 63;
  const int wave = threadIdx.x >> 6;
  const int g = lane >> 4;
  const int r16 = lane & 15;
  const int m0 = blockIdx.x * 64 + wave * 16;

  f32x4 acc[12];
#pragma unroll
  for (int jt = 0; jt < 12; ++jt) {
    acc[jt][0] = 0.f; acc[jt][1] = 0.f; acc[jt][2] = 0.f; acc[jt][3] = 0.f;
  }
#pragma unroll
  for (int cc = 0; cc < 6; ++cc) {
    f16x8 af = *((const f16x8*)(x16 + (size_t)(m0 + r16) * DIM + cc * 32 + g * 8));
#pragma unroll
    for (int jt = 0; jt < 12; ++jt) {
      f16x8 bf = *((const f16x8*)(w16 + (size_t)(jt * 16 + r16) * DIM + cc * 32 + g * 8));
      acc[jt] = __builtin_amdgcn_mfma_f32_16x16x32_f16(af, bf, acc[jt], 0, 0, 0);
    }
  }
#pragma unroll
  for (int jt = 0; jt < 12; ++jt) {
    int j = jt * 16 + r16;
    float bias = pb[j];
#pragma unroll
    for (int r = 0; r < 4; ++r) {
      out[(size_t)(m0 + g * 4 + r) * DIM + j] = acc[jt][r] + bias;
    }
  }
}

// ---------------------------------------------------------------------------
extern "C" void kernel_launch(void* const* d_in, const int* in_sizes, int n_in,
                              void* d_out, int out_size, void* d_ws, size_t ws_size,
                              hipStream_t stream) {
  const float* qkv  = (const float*)d_in[0];
  const int*   rpi  = (const int*)d_in[1];
  const float* mask = (const float*)d_in[2];
  const float* rpb  = (const float*)d_in[3];
  const float* pw   = (const float*)d_in[4];
  const float* pbv  = (const float*)d_in[5];
  float* out = (float*)d_out;

  char* ws = (char*)d_ws;
  f16* cb  = (f16*)ws;                               // 12,582,912 B
  f16* x16 = (f16*)(ws + 12582912);                  // 25,165,824 B
  f16* w16 = (f16*)(ws + 12582912 + 25165824);       // 73,728 B

  prep_cb_kernel<<<24576, 256, 0, stream>>>(rpi, mask, rpb, cb);
  prep_w_kernel<<<144, 256, 0, stream>>>(pw, w16);
  attn_kernel<<<3072, 256, 0, stream>>>(qkv, cb, x16);
  proj_kernel<<<1024, 256, 0, stream>>>(x16, w16, pbv, out);
}

// Round 6
// 122.349 us; speedup vs baseline: 1.3263x; 1.0347x over previous
//
#include <hip/hip_runtime.h>
#include <hip/hip_bf16.h>

typedef _Float16 f16;
typedef _Float16 f16x2 __attribute__((ext_vector_type(2)));
typedef _Float16 f16x4 __attribute__((ext_vector_type(4)));
typedef _Float16 f16x8 __attribute__((ext_vector_type(8)));
typedef __fp16 h16x2 __attribute__((ext_vector_type(2)));
typedef float f32x4 __attribute__((ext_vector_type(4)));

// Problem constants
#define NHEADS 6
#define NTOK 256      // tokens per window
#define NWINS 256     // windows (b_)
#define DIM 192
#define HD 32
#define C3 576        // 3*DIM
#define LOG2E 1.4426950408889634f
// Q scale folded with log2e: softmax uses exp2 directly (raw v_exp_f32)
#define SCALE (0.17677669529663687f * LOG2E)

// packed f32x2 -> f16x2 (v_cvt_pkrtz_f16_f32), bit-cast to _Float16 vec type
__device__ inline f16x2 pkrtz(float a, float b) {
  h16x2 r = __builtin_amdgcn_cvt_pkrtz(a, b);
  return __builtin_bit_cast(f16x2, r);
}

// ---------------------------------------------------------------------------
// Kernel 1: CB[mg][h][q][k] = (rpb_table[rpi[q,k],h] + mask[mg][q][k]) * log2e
// ---------------------------------------------------------------------------
__global__ __launch_bounds__(256) void prep_cb_kernel(const int* __restrict__ rpi,
                                                      const float* __restrict__ mask,
                                                      const float* __restrict__ rpb,
                                                      f16* __restrict__ cb) {
  int idx = blockIdx.x * 256 + threadIdx.x;
  int k = idx & 255;
  int q = (idx >> 8) & 255;
  int t = idx >> 16;       // t = mg*6 + h
  int h = t % 6;
  int mg = t / 6;
  float v = (rpb[rpi[(q << 8) | k] * 6 + h] + mask[(mg << 16) | (q << 8) | k]) * LOG2E;
  cb[idx] = (f16)v;
}

// ---------------------------------------------------------------------------
// Kernel 2: W (192x192) fp32 -> f16
// ---------------------------------------------------------------------------
__global__ __launch_bounds__(256) void prep_w_kernel(const float* __restrict__ w,
                                                     f16* __restrict__ w16) {
  int i = blockIdx.x * 256 + threadIdx.x;
  if (i < DIM * DIM) w16[i] = (f16)w[i];
}

__device__ inline f16x8 q_to_f16(float4 a, float4 b) {
  f16x2 p0 = pkrtz(a.x * SCALE, a.y * SCALE);
  f16x2 p1 = pkrtz(a.z * SCALE, a.w * SCALE);
  f16x2 p2 = pkrtz(b.x * SCALE, b.y * SCALE);
  f16x2 p3 = pkrtz(b.z * SCALE, b.w * SCALE);
  f16x4 lo = __builtin_shufflevector(p0, p1, 0, 1, 2, 3);
  f16x4 hi = __builtin_shufflevector(p2, p3, 0, 1, 2, 3);
  return __builtin_shufflevector(lo, hi, 0, 1, 2, 3, 4, 5, 6, 7);
}

// ---------------------------------------------------------------------------
// Kernel 3: fused window attention. Block = (b, h). 256 thr = 4 waves.
// Wave w handles q rows [w*64, w*64+64) in 4 chunks of 16 (K/V staged ONCE).
//
// r5: q-halves merged (staging amortized over 2x compute); exp2-folded scale;
// packed f16 cvts (cvt_pkrtz); 4-chain max/sum reductions.
//
// S^T = K . Q^T via mfma_f32_16x16x32_f16; C: q-col=(l&15), key=kt*16+4*(l>>4)+r
// X^T = V^T . P^T via mfma_f32_16x16x16f16: P^T C-layout == B-operand layout.
// ---------------------------------------------------------------------------
__global__ __launch_bounds__(256, 3) void attn_kernel(const float* __restrict__ qkv,
                                                      const f16* __restrict__ cb,
                                                      f16* __restrict__ x16) {
  const int idx = blockIdx.x;
  const int b = idx & 255;
  const int h = idx >> 8;
  const int tid = threadIdx.x;
  const int lane = tid & 63;
  const int wave = tid >> 6;
  const int g = lane >> 4;
  const int r16 = lane & 15;

  __shared__ f16 Klin[16 * 64 * 8];   // frag-linear (XOR-swizzled), 16 KB
  __shared__ f16 VT[32][264];         // [d][key^((d&7)<<2)] padded

  const int qbase = wave * 64;
  const size_t cb_base = ((size_t)((b & 15) * 6 + h)) << 16;
  const f16* cbp = cb + cb_base + ((size_t)(qbase + r16) << 8) + g * 4;

  // ---- batch-issue staging loads: group A (rows 0..127), group B (128..255)
  const int srow = tid >> 3;   // 0..31
  const int part = tid & 7;    // which 16B of the 128B row segment
  const float* kbase = qkv + (size_t)(b * NTOK + srow) * C3 + DIM + h * HD + part * 4;
  float4 ka[4], va[4], kb[4], vb[4];
#pragma unroll
  for (int rg = 0; rg < 4; ++rg) {
    const float* kp = kbase + (size_t)(rg * 32) * C3;
    ka[rg] = *(const float4*)kp;
    va[rg] = *(const float4*)(kp + DIM);
  }
#pragma unroll
  for (int rg = 0; rg < 4; ++rg) {
    const float* kp = kbase + (size_t)(rg * 32 + 128) * C3;
    kb[rg] = *(const float4*)kp;
    vb[rg] = *(const float4*)(kp + DIM);
  }

  // ---- prefetch chunk0 bias (16 x 8B, L2/L3) while staging loads fly ----
  f16x4 cv[16];
#pragma unroll
  for (int i = 0; i < 16; ++i) cv[i] = *((const f16x4*)(cbp + i * 16));

  // ---- Q load for chunk 0 ----
  const float* qp = qkv + (size_t)(b * NTOK + qbase + r16) * C3 + h * HD + g * 8;
  float4 qn0 = ((const float4*)qp)[0];
  float4 qn1 = ((const float4*)qp)[1];

  // ---- convert + LDS-write staging groups (in load order) ----
  const int gg = part >> 1;
  const int half = part & 1;
  const int d0 = part * 4;
#pragma unroll
  for (int rg = 0; rg < 4; ++rg) {
    const int row = rg * 32 + srow;
    const int slot = ((row >> 4) * 64) + gg * 16 + ((row & 15) ^ (gg << 2));
    f16x2 k01 = pkrtz(ka[rg].x, ka[rg].y);
    f16x2 k23 = pkrtz(ka[rg].z, ka[rg].w);
    *((f16x4*)&Klin[slot * 8 + half * 4]) = __builtin_shufflevector(k01, k23, 0, 1, 2, 3);
    VT[d0 + 0][row ^ (((d0 + 0) & 7) << 2)] = (f16)va[rg].x;
    VT[d0 + 1][row ^ (((d0 + 1) & 7) << 2)] = (f16)va[rg].y;
    VT[d0 + 2][row ^ (((d0 + 2) & 7) << 2)] = (f16)va[rg].z;
    VT[d0 + 3][row ^ (((d0 + 3) & 7) << 2)] = (f16)va[rg].w;
  }
#pragma unroll
  for (int rg = 0; rg < 4; ++rg) {
    const int row = rg * 32 + srow + 128;
    const int slot = ((row >> 4) * 64) + gg * 16 + ((row & 15) ^ (gg << 2));
    f16x2 k01 = pkrtz(kb[rg].x, kb[rg].y);
    f16x2 k23 = pkrtz(kb[rg].z, kb[rg].w);
    *((f16x4*)&Klin[slot * 8 + half * 4]) = __builtin_shufflevector(k01, k23, 0, 1, 2, 3);
    VT[d0 + 0][row ^ (((d0 + 0) & 7) << 2)] = (f16)vb[rg].x;
    VT[d0 + 1][row ^ (((d0 + 1) & 7) << 2)] = (f16)vb[rg].y;
    VT[d0 + 2][row ^ (((d0 + 2) & 7) << 2)] = (f16)vb[rg].z;
    VT[d0 + 3][row ^ (((d0 + 3) & 7) << 2)] = (f16)vb[rg].w;
  }

  f16x8 qf = q_to_f16(qn0, qn1);   // chunk 0 Q (scale incl. log2e)

  __syncthreads();

  // swizzled Klin read offset for this lane
  const int krd = (lane & 48) + ((lane & 15) ^ ((lane >> 2) & 12));

#pragma unroll
  for (int c = 0; c < 4; ++c) {
    f32x4 acc[16];
#pragma unroll
    for (int kt = 0; kt < 16; ++kt) {
      acc[kt][0] = 0.f; acc[kt][1] = 0.f; acc[kt][2] = 0.f; acc[kt][3] = 0.f;
    }
#pragma unroll
    for (int kt = 0; kt < 16; ++kt) {
      f16x8 af = *((const f16x8*)&Klin[(kt * 64 + krd) * 8]);
      acc[kt] = __builtin_amdgcn_mfma_f32_16x16x32_f16(af, qf, acc[kt], 0, 0, 0);
    }

    // bias + max: 4 independent chains (cuts 63-deep serial fmax to ~17)
    float m0 = -1e30f, m1 = -1e30f, m2 = -1e30f, m3 = -1e30f;
#pragma unroll
    for (int kt = 0; kt < 16; ++kt) {
      acc[kt][0] += (float)cv[kt][0];
      acc[kt][1] += (float)cv[kt][1];
      acc[kt][2] += (float)cv[kt][2];
      acc[kt][3] += (float)cv[kt][3];
      m0 = fmaxf(m0, acc[kt][0]);
      m1 = fmaxf(m1, acc[kt][1]);
      m2 = fmaxf(m2, acc[kt][2]);
      m3 = fmaxf(m3, acc[kt][3]);
    }

    // issue next chunk's cb + Q loads now (hidden under softmax + PV)
    if (c < 3) {
      const f16* cbn = cbp + (c + 1) * 4096;
#pragma unroll
      for (int i = 0; i < 16; ++i) cv[i] = *((const f16x4*)(cbn + i * 16));
      const float* qpn = qp + (size_t)((c + 1) * 16) * C3;
      qn0 = ((const float4*)qpn)[0];
      qn1 = ((const float4*)qpn)[1];
    }

    float m = fmaxf(fmaxf(m0, m1), fmaxf(m2, m3));
    m = fmaxf(m, __shfl_xor(m, 16));
    m = fmaxf(m, __shfl_xor(m, 32));

    // p = exp2(acc - m); 4-chain sums
    float s0 = 0.f, s1 = 0.f, s2 = 0.f, s3 = 0.f;
#pragma unroll
    for (int kt = 0; kt < 16; ++kt) {
      float p0 = __builtin_amdgcn_exp2f(acc[kt][0] - m);
      float p1 = __builtin_amdgcn_exp2f(acc[kt][1] - m);
      float p2 = __builtin_amdgcn_exp2f(acc[kt][2] - m);
      float p3 = __builtin_amdgcn_exp2f(acc[kt][3] - m);
      acc[kt][0] = p0; acc[kt][1] = p1; acc[kt][2] = p2; acc[kt][3] = p3;
      s0 += p0; s1 += p1; s2 += p2; s3 += p3;
    }
    float s = (s0 + s1) + (s2 + s3);
    s += __shfl_xor(s, 16);
    s += __shfl_xor(s, 32);
    const float rinv = 1.0f / s;

    // PV: X^T[d][q] = sum_k V^T[d][k] * P^T[k][q]
    f32x4 xacc[2];
#pragma unroll
    for (int dt = 0; dt < 2; ++dt) {
      xacc[dt][0] = 0.f; xacc[dt][1] = 0.f; xacc[dt][2] = 0.f; xacc[dt][3] = 0.f;
    }
#pragma unroll
    for (int kt = 0; kt < 16; ++kt) {
      f16x2 p01 = pkrtz(acc[kt][0], acc[kt][1]);
      f16x2 p23 = pkrtz(acc[kt][2], acc[kt][3]);
      f16x4 pf = __builtin_shufflevector(p01, p23, 0, 1, 2, 3);
#pragma unroll
      for (int dt = 0; dt < 2; ++dt) {
        const int vrow = dt * 16 + r16;
        const int col = (kt * 16 + g * 4) ^ ((r16 & 7) << 2);
        f16x4 vf = *((const f16x4*)&VT[vrow][col]);
        xacc[dt] = __builtin_amdgcn_mfma_f32_16x16x16f16(vf, pf, xacc[dt], 0, 0, 0);
      }
    }

    // write x (f16) [b][token][192], normalized
    f16* xp = x16 + (size_t)(b * NTOK + qbase + c * 16 + r16) * DIM + h * HD;
#pragma unroll
    for (int dt = 0; dt < 2; ++dt) {
      f16x2 o01 = pkrtz(xacc[dt][0] * rinv, xacc[dt][1] * rinv);
      f16x2 o23 = pkrtz(xacc[dt][2] * rinv, xacc[dt][3] * rinv);
      *((f16x4*)(xp + dt * 16 + g * 4)) = __builtin_shufflevector(o01, o23, 0, 1, 2, 3);
    }

    // convert next chunk's Q (raw loads already in flight)
    if (c < 3) qf = q_to_f16(qn0, qn1);
  }
}

// ---------------------------------------------------------------------------
// Kernel 4: out[m][j] = sum_c X16[m][c] * W16[j][c] + pb[j]
// ---------------------------------------------------------------------------
__global__ __launch_bounds__(256) void proj_kernel(const f16* __restrict__ x16,
                                                   const f16* __restrict__ w16,
                                                   const float* __restrict__ pb,
                                                   float* __restrict__ out) {
  const int lane = threadIdx.x & 63;
  const int wave = threadIdx.x >> 6;
  const int g = lane >> 4;
  const int r16 = lane & 15;
  const int m0 = blockIdx.x * 64 + wave * 16;

  f32x4 acc[12];
#pragma unroll
  for (int jt = 0; jt < 12; ++jt) {
    acc[jt][0] = 0.f; acc[jt][1] = 0.f; acc[jt][2] = 0.f; acc[jt][3] = 0.f;
  }
#pragma unroll
  for (int cc = 0; cc < 6; ++cc) {
    f16x8 af = *((const f16x8*)(x16 + (size_t)(m0 + r16) * DIM + cc * 32 + g * 8));
#pragma unroll
    for (int jt = 0; jt < 12; ++jt) {
      f16x8 bf = *((const f16x8*)(w16 + (size_t)(jt * 16 + r16) * DIM + cc * 32 + g * 8));
      acc[jt] = __builtin_amdgcn_mfma_f32_16x16x32_f16(af, bf, acc[jt], 0, 0, 0);
    }
  }
#pragma unroll
  for (int jt = 0; jt < 12; ++jt) {
    int j = jt * 16 + r16;
    float bias = pb[j];
#pragma unroll
    for (int r = 0; r < 4; ++r) {
      out[(size_t)(m0 + g * 4 + r) * DIM + j] = acc[jt][r] + bias;
    }
  }
}

// ---------------------------------------------------------------------------
extern "C" void kernel_launch(void* const* d_in, const int* in_sizes, int n_in,
                              void* d_out, int out_size, void* d_ws, size_t ws_size,
                              hipStream_t stream) {
  const float* qkv  = (const float*)d_in[0];
  const int*   rpi  = (const int*)d_in[1];
  const float* mask = (const float*)d_in[2];
  const float* rpb  = (const float*)d_in[3];
  const float* pw   = (const float*)d_in[4];
  const float* pbv  = (const float*)d_in[5];
  float* out = (float*)d_out;

  char* ws = (char*)d_ws;
  f16* cb  = (f16*)ws;                               // 12,582,912 B
  f16* x16 = (f16*)(ws + 12582912);                  // 25,165,824 B
  f16* w16 = (f16*)(ws + 12582912 + 25165824);       // 73,728 B

  prep_cb_kernel<<<24576, 256, 0, stream>>>(rpi, mask, rpb, cb);
  prep_w_kernel<<<144, 256, 0, stream>>>(pw, w16);
  attn_kernel<<<1536, 256, 0, stream>>>(qkv, cb, x16);
  proj_kernel<<<1024, 256, 0, stream>>>(x16, w16, pbv, out);
}

// Round 8
// 119.951 us; speedup vs baseline: 1.3529x; 1.0200x over previous
//
#include <hip/hip_runtime.h>
#include <hip/hip_bf16.h>

typedef _Float16 f16;
typedef _Float16 f16x2 __attribute__((ext_vector_type(2)));
typedef _Float16 f16x4 __attribute__((ext_vector_type(4)));
typedef _Float16 f16x8 __attribute__((ext_vector_type(8)));
typedef __fp16 h16x2 __attribute__((ext_vector_type(2)));
typedef float f32x4 __attribute__((ext_vector_type(4)));

// Problem constants
#define NHEADS 6
#define NTOK 256      // tokens per window
#define NWINS 256     // windows (b_)
#define DIM 192
#define HD 32
#define C3 576        // 3*DIM
#define LOG2E 1.4426950408889634f
// Q scale folded with log2e: softmax uses exp2 directly (raw v_exp_f32)
#define SCALE (0.17677669529663687f * LOG2E)

// packed f32x2 -> f16x2 (v_cvt_pkrtz_f16_f32), bit-cast to _Float16 vec type
__device__ inline f16x2 pkrtz(float a, float b) {
  h16x2 r = __builtin_amdgcn_cvt_pkrtz(a, b);
  return __builtin_bit_cast(f16x2, r);
}

// ---------------------------------------------------------------------------
// Kernel 1: CB[mg][h][q][k] = (rpb_table[rpi[q,k],h] + mask[mg][q][k]) * log2e
// ---------------------------------------------------------------------------
__global__ __launch_bounds__(256) void prep_cb_kernel(const int* __restrict__ rpi,
                                                      const float* __restrict__ mask,
                                                      const float* __restrict__ rpb,
                                                      f16* __restrict__ cb) {
  int idx = blockIdx.x * 256 + threadIdx.x;
  int k = idx & 255;
  int q = (idx >> 8) & 255;
  int t = idx >> 16;       // t = mg*6 + h
  int h = t % 6;
  int mg = t / 6;
  float v = (rpb[rpi[(q << 8) | k] * 6 + h] + mask[(mg << 16) | (q << 8) | k]) * LOG2E;
  cb[idx] = (f16)v;
}

// ---------------------------------------------------------------------------
// Kernel 2: W (192x192) fp32 -> f16
// ---------------------------------------------------------------------------
__global__ __launch_bounds__(256) void prep_w_kernel(const float* __restrict__ w,
                                                     f16* __restrict__ w16) {
  int i = blockIdx.x * 256 + threadIdx.x;
  if (i < DIM * DIM) w16[i] = (f16)w[i];
}

__device__ inline f16x8 q_to_f16(float4 a, float4 b) {
  f16x2 p0 = pkrtz(a.x * SCALE, a.y * SCALE);
  f16x2 p1 = pkrtz(a.z * SCALE, a.w * SCALE);
  f16x2 p2 = pkrtz(b.x * SCALE, b.y * SCALE);
  f16x2 p3 = pkrtz(b.z * SCALE, b.w * SCALE);
  f16x4 lo = __builtin_shufflevector(p0, p1, 0, 1, 2, 3);
  f16x4 hi = __builtin_shufflevector(p2, p3, 0, 1, 2, 3);
  return __builtin_shufflevector(lo, hi, 0, 1, 2, 3, 4, 5, 6, 7);
}

// ---------------------------------------------------------------------------
// Kernel 3: fused window attention. Block = (b, h). 256 thr = 4 waves.
// Wave w handles q rows [w*64, w*64+64) in 4 chunks of 16 (K/V staged ONCE).
//
// r7/r8: ONLINE SOFTMAX over 2 k-halves -> S-tile regs halve (acc[8]=32).
// Peak unified regs ~100 -> __launch_bounds__(256,4) (128 cap) without spill
// -> 4 waves/SIMD resident (was 2.3).
// r8 FIX: denominator s must be reduced across the 4-lane q-row group
// (shfl_xor 16/32) — r7 dropped it, giving ~4x-too-large outputs.
//
// S^T = K . Q^T via mfma_f32_16x16x32_f16; C: q-col=(l&15), key=kt*16+4*(l>>4)+r
// X^T = V^T . P^T via mfma_f32_16x16x16f16: P^T C-layout == B-operand layout.
// ---------------------------------------------------------------------------
__global__ __launch_bounds__(256, 4) void attn_kernel(const float* __restrict__ qkv,
                                                      const f16* __restrict__ cb,
                                                      f16* __restrict__ x16) {
  const int idx = blockIdx.x;
  const int b = idx & 255;
  const int h = idx >> 8;
  const int tid = threadIdx.x;
  const int lane = tid & 63;
  const int wave = tid >> 6;
  const int g = lane >> 4;
  const int r16 = lane & 15;

  __shared__ f16 Klin[16 * 64 * 8];   // frag-linear (XOR-swizzled), 16 KB
  __shared__ f16 VT[32][264];         // [d][key^((d&7)<<2)] padded

  const int qbase = wave * 64;
  const size_t cb_base = ((size_t)((b & 15) * 6 + h)) << 16;
  const f16* cbp = cb + cb_base + ((size_t)(qbase + r16) << 8) + g * 4;

  // ---- batch-issue staging loads: group A (rows 0..127), group B (128..255)
  const int srow = tid >> 3;   // 0..31
  const int part = tid & 7;    // which 16B of the 128B row segment
  const float* kbase = qkv + (size_t)(b * NTOK + srow) * C3 + DIM + h * HD + part * 4;
  float4 ka[4], va[4], kb[4], vb[4];
#pragma unroll
  for (int rg = 0; rg < 4; ++rg) {
    const float* kp = kbase + (size_t)(rg * 32) * C3;
    ka[rg] = *(const float4*)kp;
    va[rg] = *(const float4*)(kp + DIM);
  }
#pragma unroll
  for (int rg = 0; rg < 4; ++rg) {
    const float* kp = kbase + (size_t)(rg * 32 + 128) * C3;
    kb[rg] = *(const float4*)kp;
    vb[rg] = *(const float4*)(kp + DIM);
  }

  // ---- prefetch chunk0 phase-A bias (8 x 8B, L2/L3) while staging flies ----
  f16x4 cvA[8], cvB[8];
#pragma unroll
  for (int i = 0; i < 8; ++i) cvA[i] = *((const f16x4*)(cbp + i * 16));

  // ---- Q load for chunk 0 ----
  const float* qp = qkv + (size_t)(b * NTOK + qbase + r16) * C3 + h * HD + g * 8;
  float4 qn0 = ((const float4*)qp)[0];
  float4 qn1 = ((const float4*)qp)[1];

  // ---- convert + LDS-write staging groups (in load order) ----
  const int gg = part >> 1;
  const int half = part & 1;
  const int d0 = part * 4;
#pragma unroll
  for (int rg = 0; rg < 4; ++rg) {
    const int row = rg * 32 + srow;
    const int slot = ((row >> 4) * 64) + gg * 16 + ((row & 15) ^ (gg << 2));
    f16x2 k01 = pkrtz(ka[rg].x, ka[rg].y);
    f16x2 k23 = pkrtz(ka[rg].z, ka[rg].w);
    *((f16x4*)&Klin[slot * 8 + half * 4]) = __builtin_shufflevector(k01, k23, 0, 1, 2, 3);
    VT[d0 + 0][row ^ (((d0 + 0) & 7) << 2)] = (f16)va[rg].x;
    VT[d0 + 1][row ^ (((d0 + 1) & 7) << 2)] = (f16)va[rg].y;
    VT[d0 + 2][row ^ (((d0 + 2) & 7) << 2)] = (f16)va[rg].z;
    VT[d0 + 3][row ^ (((d0 + 3) & 7) << 2)] = (f16)va[rg].w;
  }
#pragma unroll
  for (int rg = 0; rg < 4; ++rg) {
    const int row = rg * 32 + srow + 128;
    const int slot = ((row >> 4) * 64) + gg * 16 + ((row & 15) ^ (gg << 2));
    f16x2 k01 = pkrtz(kb[rg].x, kb[rg].y);
    f16x2 k23 = pkrtz(kb[rg].z, kb[rg].w);
    *((f16x4*)&Klin[slot * 8 + half * 4]) = __builtin_shufflevector(k01, k23, 0, 1, 2, 3);
    VT[d0 + 0][row ^ (((d0 + 0) & 7) << 2)] = (f16)vb[rg].x;
    VT[d0 + 1][row ^ (((d0 + 1) & 7) << 2)] = (f16)vb[rg].y;
    VT[d0 + 2][row ^ (((d0 + 2) & 7) << 2)] = (f16)vb[rg].z;
    VT[d0 + 3][row ^ (((d0 + 3) & 7) << 2)] = (f16)vb[rg].w;
  }

  f16x8 qf = q_to_f16(qn0, qn1);   // chunk 0 Q (scale incl. log2e)

  __syncthreads();

  // swizzled Klin read offset for this lane
  const int krd = (lane & 48) + ((lane & 15) ^ ((lane >> 2) & 12));

#pragma unroll
  for (int c = 0; c < 4; ++c) {
    // ================= phase A: keys 0..127 =================
    f32x4 acc[8];
#pragma unroll
    for (int kt = 0; kt < 8; ++kt) {
      acc[kt][0] = 0.f; acc[kt][1] = 0.f; acc[kt][2] = 0.f; acc[kt][3] = 0.f;
    }
#pragma unroll
    for (int kt = 0; kt < 8; ++kt) {
      f16x8 af = *((const f16x8*)&Klin[(kt * 64 + krd) * 8]);
      acc[kt] = __builtin_amdgcn_mfma_f32_16x16x32_f16(af, qf, acc[kt], 0, 0, 0);
    }

    // issue phase-B bias loads (consumed after phase-A softmax+PV)
    const f16* cbc = cbp + c * 4096;
#pragma unroll
    for (int i = 0; i < 8; ++i) cvB[i] = *((const f16x4*)(cbc + (8 + i) * 16));

    // bias + max: 4 independent chains
    float m0 = -1e30f, m1 = -1e30f, m2 = -1e30f, m3 = -1e30f;
#pragma unroll
    for (int kt = 0; kt < 8; ++kt) {
      acc[kt][0] += (float)cvA[kt][0];
      acc[kt][1] += (float)cvA[kt][1];
      acc[kt][2] += (float)cvA[kt][2];
      acc[kt][3] += (float)cvA[kt][3];
      m0 = fmaxf(m0, acc[kt][0]);
      m1 = fmaxf(m1, acc[kt][1]);
      m2 = fmaxf(m2, acc[kt][2]);
      m3 = fmaxf(m3, acc[kt][3]);
    }
    float mA = fmaxf(fmaxf(m0, m1), fmaxf(m2, m3));
    mA = fmaxf(mA, __shfl_xor(mA, 16));
    mA = fmaxf(mA, __shfl_xor(mA, 32));

    float s0 = 0.f, s1 = 0.f, s2 = 0.f, s3 = 0.f;
#pragma unroll
    for (int kt = 0; kt < 8; ++kt) {
      float p0 = __builtin_amdgcn_exp2f(acc[kt][0] - mA);
      float p1 = __builtin_amdgcn_exp2f(acc[kt][1] - mA);
      float p2 = __builtin_amdgcn_exp2f(acc[kt][2] - mA);
      float p3 = __builtin_amdgcn_exp2f(acc[kt][3] - mA);
      acc[kt][0] = p0; acc[kt][1] = p1; acc[kt][2] = p2; acc[kt][3] = p3;
      s0 += p0; s1 += p1; s2 += p2; s3 += p3;
    }
    float sA = (s0 + s1) + (s2 + s3);

    // PV phase A
    f32x4 xacc[2];
    xacc[0][0] = 0.f; xacc[0][1] = 0.f; xacc[0][2] = 0.f; xacc[0][3] = 0.f;
    xacc[1][0] = 0.f; xacc[1][1] = 0.f; xacc[1][2] = 0.f; xacc[1][3] = 0.f;
#pragma unroll
    for (int kt = 0; kt < 8; ++kt) {
      f16x2 p01 = pkrtz(acc[kt][0], acc[kt][1]);
      f16x2 p23 = pkrtz(acc[kt][2], acc[kt][3]);
      f16x4 pf = __builtin_shufflevector(p01, p23, 0, 1, 2, 3);
#pragma unroll
      for (int dt = 0; dt < 2; ++dt) {
        const int col = (kt * 16 + g * 4) ^ ((r16 & 7) << 2);
        f16x4 vf = *((const f16x4*)&VT[dt * 16 + r16][col]);
        xacc[dt] = __builtin_amdgcn_mfma_f32_16x16x16f16(vf, pf, xacc[dt], 0, 0, 0);
      }
    }

    // ================= phase B: keys 128..255 =================
#pragma unroll
    for (int kt = 0; kt < 8; ++kt) {
      acc[kt][0] = 0.f; acc[kt][1] = 0.f; acc[kt][2] = 0.f; acc[kt][3] = 0.f;
    }
#pragma unroll
    for (int kt = 0; kt < 8; ++kt) {
      f16x8 af = *((const f16x8*)&Klin[((kt + 8) * 64 + krd) * 8]);
      acc[kt] = __builtin_amdgcn_mfma_f32_16x16x32_f16(af, qf, acc[kt], 0, 0, 0);
    }

    // prefetch next chunk's phase-A bias + Q (hidden under phase-B tail)
    if (c < 3) {
#pragma unroll
      for (int i = 0; i < 8; ++i) cvA[i] = *((const f16x4*)(cbc + 4096 + i * 16));
      const float* qpn = qp + (size_t)((c + 1) * 16) * C3;
      qn0 = ((const float4*)qpn)[0];
      qn1 = ((const float4*)qpn)[1];
    }

    m0 = -1e30f; m1 = -1e30f; m2 = -1e30f; m3 = -1e30f;
#pragma unroll
    for (int kt = 0; kt < 8; ++kt) {
      acc[kt][0] += (float)cvB[kt][0];
      acc[kt][1] += (float)cvB[kt][1];
      acc[kt][2] += (float)cvB[kt][2];
      acc[kt][3] += (float)cvB[kt][3];
      m0 = fmaxf(m0, acc[kt][0]);
      m1 = fmaxf(m1, acc[kt][1]);
      m2 = fmaxf(m2, acc[kt][2]);
      m3 = fmaxf(m3, acc[kt][3]);
    }
    float mB = fmaxf(fmaxf(m0, m1), fmaxf(m2, m3));
    mB = fmaxf(mB, __shfl_xor(mB, 16));
    mB = fmaxf(mB, __shfl_xor(mB, 32));

    const float m = fmaxf(mA, mB);
    const float scA = __builtin_amdgcn_exp2f(mA - m);

    s0 = 0.f; s1 = 0.f; s2 = 0.f; s3 = 0.f;
#pragma unroll
    for (int kt = 0; kt < 8; ++kt) {
      float p0 = __builtin_amdgcn_exp2f(acc[kt][0] - m);
      float p1 = __builtin_amdgcn_exp2f(acc[kt][1] - m);
      float p2 = __builtin_amdgcn_exp2f(acc[kt][2] - m);
      float p3 = __builtin_amdgcn_exp2f(acc[kt][3] - m);
      acc[kt][0] = p0; acc[kt][1] = p1; acc[kt][2] = p2; acc[kt][3] = p3;
      s0 += p0; s1 += p1; s2 += p2; s3 += p3;
    }
    // per-lane partial denominator; REDUCE across the 4-lane q-row group
    // (r7 bug: this reduction was missing -> ~4x-too-large outputs)
    float s = sA * scA + (s0 + s1) + (s2 + s3);
    s += __shfl_xor(s, 16);
    s += __shfl_xor(s, 32);
    const float rinv = 1.0f / s;

    // rescale phase-A PV then accumulate phase B
    xacc[0][0] *= scA; xacc[0][1] *= scA; xacc[0][2] *= scA; xacc[0][3] *= scA;
    xacc[1][0] *= scA; xacc[1][1] *= scA; xacc[1][2] *= scA; xacc[1][3] *= scA;
#pragma unroll
    for (int kt = 0; kt < 8; ++kt) {
      f16x2 p01 = pkrtz(acc[kt][0], acc[kt][1]);
      f16x2 p23 = pkrtz(acc[kt][2], acc[kt][3]);
      f16x4 pf = __builtin_shufflevector(p01, p23, 0, 1, 2, 3);
#pragma unroll
      for (int dt = 0; dt < 2; ++dt) {
        const int col = ((kt + 8) * 16 + g * 4) ^ ((r16 & 7) << 2);
        f16x4 vf = *((const f16x4*)&VT[dt * 16 + r16][col]);
        xacc[dt] = __builtin_amdgcn_mfma_f32_16x16x16f16(vf, pf, xacc[dt], 0, 0, 0);
      }
    }

    // write x (f16) [b][token][192], normalized
    f16* xp = x16 + (size_t)(b * NTOK + qbase + c * 16 + r16) * DIM + h * HD;
#pragma unroll
    for (int dt = 0; dt < 2; ++dt) {
      f16x2 o01 = pkrtz(xacc[dt][0] * rinv, xacc[dt][1] * rinv);
      f16x2 o23 = pkrtz(xacc[dt][2] * rinv, xacc[dt][3] * rinv);
      *((f16x4*)(xp + dt * 16 + g * 4)) = __builtin_shufflevector(o01, o23, 0, 1, 2, 3);
    }

    // convert next chunk's Q (raw loads already in flight)
    if (c < 3) qf = q_to_f16(qn0, qn1);
  }
}

// ---------------------------------------------------------------------------
// Kernel 4: out[m][j] = sum_c X16[m][c] * W16[j][c] + pb[j]
// ---------------------------------------------------------------------------
__global__ __launch_bounds__(256) void proj_kernel(const f16* __restrict__ x16,
                                                   const f16* __restrict__ w16,
                                                   const float* __restrict__ pb,
                                                   float* __restrict__ out) {
  const int lane = threadIdx.x & 63;
  const int wave = threadIdx.x >> 6;
  const int g = lane >> 4;
  const int r16 = lane & 15;
  const int m0 = blockIdx.x * 64 + wave * 16;

  f32x4 acc[12];
#pragma unroll
  for (int jt = 0; jt < 12; ++jt) {
    acc[jt][0] = 0.f; acc[jt][1] = 0.f; acc[jt][2] = 0.f; acc[jt][3] = 0.f;
  }
#pragma unroll
  for (int cc = 0; cc < 6; ++cc) {
    f16x8 af = *((const f16x8*)(x16 + (size_t)(m0 + r16) * DIM + cc * 32 + g * 8));
#pragma unroll
    for (int jt = 0; jt < 12; ++jt) {
      f16x8 bf = *((const f16x8*)(w16 + (size_t)(jt * 16 + r16) * DIM + cc * 32 + g * 8));
      acc[jt] = __builtin_amdgcn_mfma_f32_16x16x32_f16(af, bf, acc[jt], 0, 0, 0);
    }
  }
#pragma unroll
  for (int jt = 0; jt < 12; ++jt) {
    int j = jt * 16 + r16;
    float bias = pb[j];
#pragma unroll
    for (int r = 0; r < 4; ++r) {
      out[(size_t)(m0 + g * 4 + r) * DIM + j] = acc[jt][r] + bias;
    }
  }
}

// ---------------------------------------------------------------------------
extern "C" void kernel_launch(void* const* d_in, const int* in_sizes, int n_in,
                              void* d_out, int out_size, void* d_ws, size_t ws_size,
                              hipStream_t stream) {
  const float* qkv  = (const float*)d_in[0];
  const int*   rpi  = (const int*)d_in[1];
  const float* mask = (const float*)d_in[2];
  const float* rpb  = (const float*)d_in[3];
  const float* pw   = (const float*)d_in[4];
  const float* pbv  = (const float*)d_in[5];
  float* out = (float*)d_out;

  char* ws = (char*)d_ws;
  f16* cb  = (f16*)ws;                               // 12,582,912 B
  f16* x16 = (f16*)(ws + 12582912);                  // 25,165,824 B
  f16* w16 = (f16*)(ws + 12582912 + 25165824);       // 73,728 B

  prep_cb_kernel<<<24576, 256, 0, stream>>>(rpi, mask, rpb, cb);
  prep_w_kernel<<<144, 256, 0, stream>>>(pw, w16);
  attn_kernel<<<1536, 256, 0, stream>>>(qkv, cb, x16);
  proj_kernel<<<1024, 256, 0, stream>>>(x16, w16, pbv, out);
}